// Round 21
// baseline (134.159 us; speedup 1.0000x reference)
//
#include <hip/hip_runtime.h>
#include <hip/hip_bf16.h>
#include <cstdint>

typedef _Float16 f16;
typedef __attribute__((ext_vector_type(8))) _Float16 f16x8;
typedef __attribute__((ext_vector_type(4))) _Float16 f16x4;
typedef __attribute__((ext_vector_type(2))) _Float16 f16x2;
typedef __attribute__((ext_vector_type(4))) float f32x4;

#define MFMA(a, b, c) __builtin_amdgcn_mfma_f32_16x16x32_f16((a), (b), (c), 0, 0, 0)

__device__ static inline void gl_lds16(const void* g, void* l) {
  __builtin_amdgcn_global_load_lds(
      (__attribute__((address_space(1))) const void*)g,
      (__attribute__((address_space(3))) void*)l, 16, 0, 0);
}

// ---------------- f32 -> f16 cast, all three tensors in one launch ----------------
__global__ __launch_bounds__(256) void cvt_all(const float* __restrict__ x,
                                               const float* __restrict__ wq,
                                               const float* __restrict__ wp,
                                               f16* __restrict__ xo,
                                               f16* __restrict__ wqo,
                                               f16* __restrict__ wpo) {
  int i = blockIdx.x * 256 + threadIdx.x;
  const float* src;
  f16* dst;
  if (i < 1572864) {
    src = x; dst = xo;
  } else if (i < 1572864 + 442368) {
    i -= 1572864; src = wq; dst = wqo;
  } else {
    i -= 1572864 + 442368;
    if (i >= 147456) return;
    src = wp; dst = wpo;
  }
  const float4 v = reinterpret_cast<const float4*>(src)[i];
  f16x4 o;
  o.x = (f16)v.x; o.y = (f16)v.y; o.z = (f16)v.z; o.w = (f16)v.w;
  reinterpret_cast<f16x4*>(dst)[i] = o;
}

// ---------------- QKV GEMM: [8192,768] x [2304,768]^T ----------------
// BK=32, 32KB LDS double-buffer, counted vmcnt + raw barriers.
// Bank swizzle for 64B rows: slot ^= (row ^ row>>2) & 3.
// Outputs: Qt [B,H,D,N] (pre-scaled), K [B,H,N,D], Vt [B,H,D,N].
__global__ __launch_bounds__(256) void gemm_qkv(const f16* __restrict__ X,
                                                const f16* __restrict__ W,
                                                f16* __restrict__ Qt,
                                                f16* __restrict__ Ko,
                                                f16* __restrict__ Vt) {
  __shared__ f16 As[2][4096];
  __shared__ f16 Bs[2][4096];
  const int tid = threadIdx.x;
  const int lane = tid & 63;
  const int w = tid >> 6;
  const int l15 = lane & 15, hi = lane >> 4;
  const int m0 = blockIdx.x * 128;
  const int n0 = blockIdx.y * 128;
  const int wr = (w >> 1) * 64;
  const int wc = (w & 1) * 64;
  f32x4 acc[4][4] = {};

  const int srow0 = tid >> 2;
  const int sslot = tid & 3;
  auto stage = [&](int buf, int k0) {
#pragma unroll
    for (int i = 0; i < 2; ++i) {
      const int row = i * 64 + srow0;
      const int gs = (sslot ^ ((row ^ (row >> 2)) & 3)) * 8;
      gl_lds16(X + (size_t)(m0 + row) * 768 + k0 + gs,
               &As[buf][row * 32 + sslot * 8]);
      gl_lds16(W + (size_t)(n0 + row) * 768 + k0 + gs,
               &Bs[buf][row * 32 + sslot * 8]);
    }
  };
  stage(0, 0);
  stage(1, 32);

  const int ko = (hi ^ ((l15 ^ (l15 >> 2)) & 3)) * 8;

#pragma unroll 1
  for (int t = 0; t < 24; ++t) {
    if (t < 23) asm volatile("s_waitcnt vmcnt(4)" ::: "memory");
    else        asm volatile("s_waitcnt vmcnt(0)" ::: "memory");
    __builtin_amdgcn_s_barrier();
    const int cb = t & 1;
    f16x8 af[4], bf[4];
#pragma unroll
    for (int i = 0; i < 4; ++i)
      af[i] = *reinterpret_cast<const f16x8*>(&As[cb][(wr + i * 16 + l15) * 32 + ko]);
#pragma unroll
    for (int j = 0; j < 4; ++j)
      bf[j] = *reinterpret_cast<const f16x8*>(&Bs[cb][(wc + j * 16 + l15) * 32 + ko]);
#pragma unroll
    for (int i = 0; i < 4; ++i)
#pragma unroll
      for (int j = 0; j < 4; ++j)
        acc[i][j] = MFMA(af[i], bf[j], acc[i][j]);
    __builtin_amdgcn_s_barrier();
    if (t < 22) stage(cb, (t + 2) * 32);
  }
  // after final barrier all waves are done with As/Bs -> reuse for transpose

  const int b = m0 >> 11;
  const int nbase = (m0 & 2047) + wr;
  const int which = n0 / 768;
  const int h = ((n0 % 768) >> 6) + (wc >> 6);
  const size_t hb = (size_t)(b * 12 + h);
  const float QSCL = 0.125f * 1.44269504088896340736f;  // SCALE * log2(e)
  f16* T = &As[0][0] + w * 1280;  // 4 waves x 1280 f16 <= 8192 f16 in As

  if (which != 1) {
    f16* dst = (which == 2) ? Vt : Qt;
    const float scl = (which == 0) ? QSCL : 1.0f;
#pragma unroll
    for (int j = 0; j < 4; ++j) {
#pragma unroll
      for (int i = 0; i < 4; ++i) {
        f16x4 vv;
#pragma unroll
        for (int r = 0; r < 4; ++r) vv[r] = (f16)(acc[i][j][r] * scl);
        *reinterpret_cast<f16x4*>(&T[l15 * 72 + i * 16 + hi * 4]) = vv;
      }
      asm volatile("s_waitcnt lgkmcnt(0)" ::: "memory");
#pragma unroll
      for (int t = 0; t < 2; ++t) {
        const f16x8 v = *reinterpret_cast<const f16x8*>(
            &T[(t * 8 + (lane >> 3)) * 72 + (lane & 7) * 8]);
        const int d = j * 16 + t * 8 + (lane >> 3);
        *reinterpret_cast<f16x8*>(
            &dst[(hb * 64 + d) * 2048 + nbase + (lane & 7) * 8]) = v;
      }
      asm volatile("s_waitcnt lgkmcnt(0)" ::: "memory");
    }
  } else {
#pragma unroll
    for (int i = 0; i < 4; ++i) {
#pragma unroll
      for (int j = 0; j < 4; ++j)
#pragma unroll
        for (int r = 0; r < 4; ++r)
          T[(hi * 4 + r) * 72 + j * 16 + l15] = (f16)acc[i][j][r];
      asm volatile("s_waitcnt lgkmcnt(0)" ::: "memory");
#pragma unroll
      for (int t = 0; t < 2; ++t) {
        const f16x8 v = *reinterpret_cast<const f16x8*>(
            &T[(t * 8 + (lane >> 3)) * 72 + (lane & 7) * 8]);
        const int n = nbase + i * 16 + t * 8 + (lane >> 3);
        *reinterpret_cast<f16x8*>(
            &Ko[(hb * 2048 + n) * 64 + (lane & 7) * 8]) = v;
      }
      asm volatile("s_waitcnt lgkmcnt(0)" ::: "memory");
    }
  }
}

// ---------------- flash attention, in-block KV-split + K32 PV (sigma) ----------------
// (frozen from R17/R18)
__global__ __launch_bounds__(256, 2) void attn_fwd(const f16* __restrict__ Qt,
                                                   const f16* __restrict__ K,
                                                   const f16* __restrict__ Vt,
                                                   f16* __restrict__ Ao) {
  __shared__ char smem[49152];
  const int tid = threadIdx.x, lane = tid & 63, w = tid >> 6;
  const int l15 = lane & 15, hi = lane >> 4;
  const int half = tid >> 7;
  const int ptd = tid & 127;

  const int id = blockIdx.x;
  const int sw = (id & 7) * 96 + (id >> 3);
  const int bh = sw >> 4;
  const int qt = sw & 15;
  const int b = bh / 12, h = bh % 12;
  const int q0 = qt * 128 + (w & 1) * 64;
  const f16* Qp = Qt + (size_t)bh * 64 * 2048;
  const f16* Kp = K + (size_t)bh * 2048 * 64;
  const f16* Vp = Vt + (size_t)bh * 64 * 2048;

  char* hbm = smem + half * 24576;
  const int kvb = half * 1024;

  const int tr = ptd >> 3;
  const int ss = ptd & 7;
  const int ssw = ss ^ (tr & 7);
  const f16* ksrc0 = Kp + (size_t)(kvb + tr) * 64 + ssw * 8;
  const f16* vsrc0 = Vp + (size_t)tr * 2048 + kvb + ssw * 8;
  char* kdst = hbm + tr * 128 + ss * 16;
  char* vdst = hbm + 16384 + tr * 128 + ss * 16;

  auto stageK = [&](int tt, int bufo) {
#pragma unroll
    for (int i = 0; i < 4; ++i)
      gl_lds16(ksrc0 + (size_t)(tt * 64 + i * 16) * 64, kdst + bufo + i * 2048);
  };
  auto stageV = [&](int tt) {
#pragma unroll
    for (int i = 0; i < 4; ++i)
      gl_lds16(vsrc0 + (size_t)i * 32768 + tt * 64, vdst + i * 2048);
  };

  stageV(0);
  stageK(0, 0);
  stageK(1, 8192);

  f16x8 qf[4][2];
#pragma unroll
  for (int mi = 0; mi < 4; ++mi)
#pragma unroll
    for (int kk = 0; kk < 2; ++kk) {
      f16x8 v;
#pragma unroll
      for (int e = 0; e < 8; ++e)
        v[e] = Qp[(size_t)(kk * 32 + hi * 8 + e) * 2048 + q0 + mi * 16 + l15];
      qf[mi][kk] = v;
    }

  const char* kb[2];
#pragma unroll
  for (int kk = 0; kk < 2; ++kk)
    kb[kk] = hbm + l15 * 128 + (((kk * 4 + hi) ^ (l15 & 7)) << 4);
  const char* vbp[2][2];
#pragma unroll
  for (int p = 0; p < 2; ++p)
#pragma unroll
    for (int c = 0; c < 2; ++c)
      vbp[p][c] = hbm + 16384 + l15 * 128 +
                  ((((4 * p + 2 * c + (hi >> 1)) ^ (l15 & 7)) << 4) + (hi & 1) * 8);

  f32x4 o[4][4] = {};
  f32x4 lacc[4] = {};
  const f32x4 Z4 = {0.f, 0.f, 0.f, 0.f};
  const f16x8 ONES8 = {(f16)1.f, (f16)1.f, (f16)1.f, (f16)1.f,
                       (f16)1.f, (f16)1.f, (f16)1.f, (f16)1.f};

#pragma unroll 1
  for (int t = 0; t < 16; ++t) {
    if (t < 15) asm volatile("s_waitcnt vmcnt(4)" ::: "memory");
    else        asm volatile("s_waitcnt vmcnt(0)" ::: "memory");
    __builtin_amdgcn_s_barrier();
    const int cbo = (t & 1) * 8192;
    f16x8 kf[4][2];
#pragma unroll
    for (int nj = 0; nj < 4; ++nj)
#pragma unroll
      for (int kk = 0; kk < 2; ++kk)
        kf[nj][kk] = *reinterpret_cast<const f16x8*>(kb[kk] + cbo + nj * 2048);
    f16x8 vf[2][4];
#pragma unroll
    for (int p = 0; p < 2; ++p)
#pragma unroll
      for (int j = 0; j < 4; ++j) {
        const f16x4 a = *reinterpret_cast<const f16x4*>(vbp[p][0] + j * 2048);
        const f16x4 c = *reinterpret_cast<const f16x4*>(vbp[p][1] + j * 2048);
        vf[p][j] = __builtin_shufflevector(a, c, 0, 1, 2, 3, 4, 5, 6, 7);
      }
    f32x4 s[4][4];
    __builtin_amdgcn_s_setprio(1);
#pragma unroll
    for (int nj = 0; nj < 4; ++nj)
#pragma unroll
      for (int mi = 0; mi < 4; ++mi) {
        s[nj][mi] = MFMA(kf[nj][0], qf[mi][0], Z4);
        s[nj][mi] = MFMA(kf[nj][1], qf[mi][1], s[nj][mi]);
      }
    __builtin_amdgcn_s_setprio(0);
    asm volatile("s_waitcnt lgkmcnt(0)" ::: "memory");
    __builtin_amdgcn_s_barrier();
    if (t < 15) stageV(t + 1);
    if (t < 14) stageK(t + 2, cbo);
    int pkx[4][4], pky[4][4];
#pragma unroll
    for (int nj = 0; nj < 4; ++nj)
#pragma unroll
      for (int mi = 0; mi < 4; ++mi) {
        f32x4 pv;
#pragma unroll
        for (int r = 0; r < 4; ++r) pv[r] = __builtin_amdgcn_exp2f(s[nj][mi][r]);
        pkx[nj][mi] = __builtin_bit_cast(int, __builtin_amdgcn_cvt_pkrtz(pv[0], pv[1]));
        pky[nj][mi] = __builtin_bit_cast(int, __builtin_amdgcn_cvt_pkrtz(pv[2], pv[3]));
      }
    __builtin_amdgcn_s_setprio(1);
#pragma unroll
    for (int p = 0; p < 2; ++p)
#pragma unroll
      for (int mi = 0; mi < 4; ++mi) {
        int4 D;
        D.x = pkx[2 * p][mi];
        D.y = pky[2 * p][mi];
        D.z = pkx[2 * p + 1][mi];
        D.w = pky[2 * p + 1][mi];
        const f16x8 bk = __builtin_bit_cast(f16x8, D);
#pragma unroll
        for (int j = 0; j < 4; ++j)
          o[j][mi] = MFMA(vf[p][j], bk, o[j][mi]);
        lacc[mi] = MFMA(ONES8, bk, lacc[mi]);
      }
    __builtin_amdgcn_s_setprio(0);
  }

  __syncthreads();
  if (w >= 2) {
    char* ob = smem + (w - 2) * 16384;
    char* lb = smem + 32768 + (w - 2) * 4096;
#pragma unroll
    for (int j = 0; j < 4; ++j)
#pragma unroll
      for (int mi = 0; mi < 4; ++mi)
        *reinterpret_cast<f32x4*>(ob + (j * 4 + mi) * 1024 + lane * 16) = o[j][mi];
#pragma unroll
    for (int mi = 0; mi < 4; ++mi)
      *reinterpret_cast<f32x4*>(lb + mi * 1024 + lane * 16) = lacc[mi];
  }
  __syncthreads();
  if (w < 2) {
    const char* ob = smem + w * 16384;
    const char* lb = smem + 32768 + w * 4096;
#pragma unroll
    for (int j = 0; j < 4; ++j)
#pragma unroll
      for (int mi = 0; mi < 4; ++mi)
        o[j][mi] += *reinterpret_cast<const f32x4*>(ob + (j * 4 + mi) * 1024 + lane * 16);
#pragma unroll
    for (int mi = 0; mi < 4; ++mi)
      lacc[mi] += *reinterpret_cast<const f32x4*>(lb + mi * 1024 + lane * 16);

    float lt[4];
#pragma unroll
    for (int mi = 0; mi < 4; ++mi) lt[mi] = 1.0f / lacc[mi][0];
    asm volatile("s_waitcnt lgkmcnt(0)" ::: "memory");
    __builtin_amdgcn_sched_barrier(0);

    f16* Pw = reinterpret_cast<f16*>(smem + w * 16384);
#pragma unroll
    for (int mi = 0; mi < 4; ++mi)
#pragma unroll
      for (int j = 0; j < 4; ++j) {
        f16x4 ok;
#pragma unroll
        for (int r = 0; r < 4; ++r) ok[r] = (f16)(o[j][mi][r] * lt[mi]);
        *reinterpret_cast<f16x4*>(&Pw[(mi * 16 + l15) * 72 + j * 16 + hi * 4]) = ok;
      }
#pragma unroll
    for (int t = 0; t < 8; ++t) {
      const f16x8 v = *reinterpret_cast<const f16x8*>(&Pw[lane * 72 + t * 8]);
      *reinterpret_cast<f16x8*>(
          &Ao[((size_t)(b * 2048 + q0 + lane)) * 768 + h * 64 + t * 8]) = v;
    }
  }
}

// ---------------- proj GEMM: [8192,768] x [768,768]^T + bias -> f32 ----------------
// Double-buffered LDS, counted vmcnt(6) + raw barriers. (R18-proven version.)
__global__ __launch_bounds__(256) void gemm_proj(const f16* __restrict__ A,
                                                 const f16* __restrict__ W,
                                                 const float* __restrict__ bias,
                                                 float* __restrict__ out) {
  __shared__ f16 As[2][4096];
  __shared__ f16 Bs[2][8192];
  const int tid = threadIdx.x;
  const int lane = tid & 63;
  const int w = tid >> 6;
  const int m0 = blockIdx.x * 64;
  const int n0 = blockIdx.y * 128;
  const int wr = (w >> 1) * 32;
  const int wc = (w & 1) * 64;
  const int srow = tid >> 3;
  const int scol = (tid & 7) * 8;
  f32x4 acc[2][4] = {};

  auto stage = [&](int buf, int k0) {
#pragma unroll
    for (int i = 0; i < 2; ++i)
      gl_lds16(A + (size_t)(m0 + i * 32 + srow) * 768 + k0 + scol,
               &As[buf][(i * 32 + srow) * 64 + scol]);
#pragma unroll
    for (int i = 0; i < 4; ++i)
      gl_lds16(W + (size_t)(n0 + i * 32 + srow) * 768 + k0 + scol,
               &Bs[buf][(i * 32 + srow) * 64 + scol]);
  };
  stage(0, 0);
  stage(1, 64);

#pragma unroll 1
  for (int t = 0; t < 12; ++t) {
    if (t < 11) asm volatile("s_waitcnt vmcnt(6)" ::: "memory");
    else        asm volatile("s_waitcnt vmcnt(0)" ::: "memory");
    __builtin_amdgcn_s_barrier();
    const int cb = t & 1;
#pragma unroll
    for (int kk = 0; kk < 2; ++kk) {
      const int ko = kk * 32 + (lane >> 4) * 8;
      f16x8 af[2], bf[4];
#pragma unroll
      for (int i = 0; i < 2; ++i)
        af[i] = *reinterpret_cast<const f16x8*>(&As[cb][(wr + i * 16 + (lane & 15)) * 64 + ko]);
#pragma unroll
      for (int j = 0; j < 4; ++j)
        bf[j] = *reinterpret_cast<const f16x8*>(&Bs[cb][(wc + j * 16 + (lane & 15)) * 64 + ko]);
#pragma unroll
      for (int i = 0; i < 2; ++i)
#pragma unroll
        for (int j = 0; j < 4; ++j)
          acc[i][j] = MFMA(af[i], bf[j], acc[i][j]);
    }
    __builtin_amdgcn_s_barrier();
    if (t < 10) stage(cb, (t + 2) * 64);
  }

#pragma unroll
  for (int j = 0; j < 4; ++j) {
    const int col = n0 + wc + j * 16 + (lane & 15);
    const float bj = bias[col];
#pragma unroll
    for (int i = 0; i < 2; ++i)
#pragma unroll
      for (int r = 0; r < 4; ++r)
        out[(size_t)(m0 + wr + i * 16 + (lane >> 4) * 4 + r) * 768 + col] =
            acc[i][j][r] + bj;
  }
}

extern "C" void kernel_launch(void* const* d_in, const int* in_sizes, int n_in,
                              void* d_out, int out_size, void* d_ws, size_t ws_size,
                              hipStream_t stream) {
  const float* x      = (const float*)d_in[0];  // [4,2048,768]
  const float* w_qkv  = (const float*)d_in[1];  // [2304,768]
  const float* w_proj = (const float*)d_in[2];  // [768,768]
  const float* b_proj = (const float*)d_in[3];  // [768]
  float* out = (float*)d_out;
  char* ws = (char*)d_ws;

  f16* xh  = (f16*)(ws);              // 8192*768*2      = 12,582,912
  f16* wqh = (f16*)(ws + 12582912);   // 2304*768*2      =  3,538,944
  f16* wph = (f16*)(ws + 16121856);   // 768*768*2       =  1,179,648
  f16* Qtb = (f16*)(ws + 17301504);   // [4,12,64,2048]  = 12,582,912
  f16* Kb  = (f16*)(ws + 29884416);   // [4,12,2048,64]
  f16* Vtb = (f16*)(ws + 42467328);   // [4,12,64,2048]
  f16* Ah  = (f16*)(ws + 55050240);   // [4,2048,768]    -> total 67,633,152 B

  cvt_all<<<8448, 256, 0, stream>>>(x, w_qkv, w_proj, xh, wqh, wph);
  gemm_qkv<<<dim3(64, 18), 256, 0, stream>>>(xh, wqh, Qtb, Kb, Vtb);
  attn_fwd<<<768, 256, 0, stream>>>(Qtb, Kb, Vtb, Ah);
  gemm_proj<<<dim3(128, 6), 256, 0, stream>>>(Ah, wph, b_proj, out);
}

// Round 22
// 134.127 us; speedup vs baseline: 1.0002x; 1.0002x over previous
//
#include <hip/hip_runtime.h>
#include <hip/hip_bf16.h>
#include <cstdint>

typedef _Float16 f16;
typedef __attribute__((ext_vector_type(8))) _Float16 f16x8;
typedef __attribute__((ext_vector_type(4))) _Float16 f16x4;
typedef __attribute__((ext_vector_type(2))) _Float16 f16x2;
typedef __attribute__((ext_vector_type(4))) float f32x4;

#define MFMA(a, b, c) __builtin_amdgcn_mfma_f32_16x16x32_f16((a), (b), (c), 0, 0, 0)

__device__ static inline void gl_lds16(const void* g, void* l) {
  __builtin_amdgcn_global_load_lds(
      (__attribute__((address_space(1))) const void*)g,
      (__attribute__((address_space(3))) void*)l, 16, 0, 0);
}

// ---------------- f32 -> f16 cast, all three tensors in one launch ----------------
__global__ __launch_bounds__(256) void cvt_all(const float* __restrict__ x,
                                               const float* __restrict__ wq,
                                               const float* __restrict__ wp,
                                               f16* __restrict__ xo,
                                               f16* __restrict__ wqo,
                                               f16* __restrict__ wpo) {
  int i = blockIdx.x * 256 + threadIdx.x;
  const float* src;
  f16* dst;
  if (i < 1572864) {
    src = x; dst = xo;
  } else if (i < 1572864 + 442368) {
    i -= 1572864; src = wq; dst = wqo;
  } else {
    i -= 1572864 + 442368;
    if (i >= 147456) return;
    src = wp; dst = wpo;
  }
  const float4 v = reinterpret_cast<const float4*>(src)[i];
  f16x4 o;
  o.x = (f16)v.x; o.y = (f16)v.y; o.z = (f16)v.z; o.w = (f16)v.w;
  reinterpret_cast<f16x4*>(dst)[i] = o;
}

// ---------------- QKV GEMM: [8192,768] x [2304,768]^T ----------------
// BK=32, 32KB LDS double-buffer, counted vmcnt + raw barriers.
// Bank swizzle for 64B rows: slot ^= (row ^ row>>2) & 3.
// Outputs: Qt [B,H,D,N] (pre-scaled), K [B,H,N,D], Vt [B,H,D,N].
__global__ __launch_bounds__(256) void gemm_qkv(const f16* __restrict__ X,
                                                const f16* __restrict__ W,
                                                f16* __restrict__ Qt,
                                                f16* __restrict__ Ko,
                                                f16* __restrict__ Vt) {
  __shared__ f16 As[2][4096];
  __shared__ f16 Bs[2][4096];
  const int tid = threadIdx.x;
  const int lane = tid & 63;
  const int w = tid >> 6;
  const int l15 = lane & 15, hi = lane >> 4;
  const int m0 = blockIdx.x * 128;
  const int n0 = blockIdx.y * 128;
  const int wr = (w >> 1) * 64;
  const int wc = (w & 1) * 64;
  f32x4 acc[4][4] = {};

  const int srow0 = tid >> 2;
  const int sslot = tid & 3;
  auto stage = [&](int buf, int k0) {
#pragma unroll
    for (int i = 0; i < 2; ++i) {
      const int row = i * 64 + srow0;
      const int gs = (sslot ^ ((row ^ (row >> 2)) & 3)) * 8;
      gl_lds16(X + (size_t)(m0 + row) * 768 + k0 + gs,
               &As[buf][row * 32 + sslot * 8]);
      gl_lds16(W + (size_t)(n0 + row) * 768 + k0 + gs,
               &Bs[buf][row * 32 + sslot * 8]);
    }
  };
  stage(0, 0);
  stage(1, 32);

  const int ko = (hi ^ ((l15 ^ (l15 >> 2)) & 3)) * 8;

#pragma unroll 1
  for (int t = 0; t < 24; ++t) {
    if (t < 23) asm volatile("s_waitcnt vmcnt(4)" ::: "memory");
    else        asm volatile("s_waitcnt vmcnt(0)" ::: "memory");
    __builtin_amdgcn_s_barrier();
    const int cb = t & 1;
    f16x8 af[4], bf[4];
#pragma unroll
    for (int i = 0; i < 4; ++i)
      af[i] = *reinterpret_cast<const f16x8*>(&As[cb][(wr + i * 16 + l15) * 32 + ko]);
#pragma unroll
    for (int j = 0; j < 4; ++j)
      bf[j] = *reinterpret_cast<const f16x8*>(&Bs[cb][(wc + j * 16 + l15) * 32 + ko]);
#pragma unroll
    for (int i = 0; i < 4; ++i)
#pragma unroll
      for (int j = 0; j < 4; ++j)
        acc[i][j] = MFMA(af[i], bf[j], acc[i][j]);
    __builtin_amdgcn_s_barrier();
    if (t < 22) stage(cb, (t + 2) * 32);
  }
  // after final barrier all waves are done with As/Bs -> reuse for transpose

  const int b = m0 >> 11;
  const int nbase = (m0 & 2047) + wr;
  const int which = n0 / 768;
  const int h = ((n0 % 768) >> 6) + (wc >> 6);
  const size_t hb = (size_t)(b * 12 + h);
  const float QSCL = 0.125f * 1.44269504088896340736f;  // SCALE * log2(e)
  f16* T = &As[0][0] + w * 1280;  // 4 waves x 1280 f16 <= 8192 f16 in As

  if (which != 1) {
    f16* dst = (which == 2) ? Vt : Qt;
    const float scl = (which == 0) ? QSCL : 1.0f;
#pragma unroll
    for (int j = 0; j < 4; ++j) {
#pragma unroll
      for (int i = 0; i < 4; ++i) {
        f16x4 vv;
#pragma unroll
        for (int r = 0; r < 4; ++r) vv[r] = (f16)(acc[i][j][r] * scl);
        *reinterpret_cast<f16x4*>(&T[l15 * 72 + i * 16 + hi * 4]) = vv;
      }
      asm volatile("s_waitcnt lgkmcnt(0)" ::: "memory");
#pragma unroll
      for (int t = 0; t < 2; ++t) {
        const f16x8 v = *reinterpret_cast<const f16x8*>(
            &T[(t * 8 + (lane >> 3)) * 72 + (lane & 7) * 8]);
        const int d = j * 16 + t * 8 + (lane >> 3);
        *reinterpret_cast<f16x8*>(
            &dst[(hb * 64 + d) * 2048 + nbase + (lane & 7) * 8]) = v;
      }
      asm volatile("s_waitcnt lgkmcnt(0)" ::: "memory");
    }
  } else {
#pragma unroll
    for (int i = 0; i < 4; ++i) {
#pragma unroll
      for (int j = 0; j < 4; ++j)
#pragma unroll
        for (int r = 0; r < 4; ++r)
          T[(hi * 4 + r) * 72 + j * 16 + l15] = (f16)acc[i][j][r];
      asm volatile("s_waitcnt lgkmcnt(0)" ::: "memory");
#pragma unroll
      for (int t = 0; t < 2; ++t) {
        const f16x8 v = *reinterpret_cast<const f16x8*>(
            &T[(t * 8 + (lane >> 3)) * 72 + (lane & 7) * 8]);
        const int n = nbase + i * 16 + t * 8 + (lane >> 3);
        *reinterpret_cast<f16x8*>(
            &Ko[(hb * 2048 + n) * 64 + (lane & 7) * 8]) = v;
      }
      asm volatile("s_waitcnt lgkmcnt(0)" ::: "memory");
    }
  }
}

// ---------------- flash attention, in-block KV-split + K32 PV (sigma) ----------------
// 4 waves/block: waves 0,1 kv[0,1024), waves 2,3 kv[1024,2048), same 128 q.
// This round: exp2/cvt_pk for fragment pair nj={0,1} hoisted into the
// pre-barrier drain window (trans pipe works while lgkm drains); nj={2,3}
// exp overlaps PV p=0 post-barrier. Pure intra-wave reorder, no sync change.
__global__ __launch_bounds__(256, 2) void attn_fwd(const f16* __restrict__ Qt,
                                                   const f16* __restrict__ K,
                                                   const f16* __restrict__ Vt,
                                                   f16* __restrict__ Ao) {
  __shared__ char smem[49152];
  const int tid = threadIdx.x, lane = tid & 63, w = tid >> 6;
  const int l15 = lane & 15, hi = lane >> 4;
  const int half = tid >> 7;
  const int ptd = tid & 127;

  const int id = blockIdx.x;
  const int sw = (id & 7) * 96 + (id >> 3);
  const int bh = sw >> 4;
  const int qt = sw & 15;
  const int b = bh / 12, h = bh % 12;
  const int q0 = qt * 128 + (w & 1) * 64;
  const f16* Qp = Qt + (size_t)bh * 64 * 2048;
  const f16* Kp = K + (size_t)bh * 2048 * 64;
  const f16* Vp = Vt + (size_t)bh * 64 * 2048;

  char* hbm = smem + half * 24576;
  const int kvb = half * 1024;

  const int tr = ptd >> 3;
  const int ss = ptd & 7;
  const int ssw = ss ^ (tr & 7);
  const f16* ksrc0 = Kp + (size_t)(kvb + tr) * 64 + ssw * 8;
  const f16* vsrc0 = Vp + (size_t)tr * 2048 + kvb + ssw * 8;
  char* kdst = hbm + tr * 128 + ss * 16;
  char* vdst = hbm + 16384 + tr * 128 + ss * 16;

  auto stageK = [&](int tt, int bufo) {
#pragma unroll
    for (int i = 0; i < 4; ++i)
      gl_lds16(ksrc0 + (size_t)(tt * 64 + i * 16) * 64, kdst + bufo + i * 2048);
  };
  auto stageV = [&](int tt) {
#pragma unroll
    for (int i = 0; i < 4; ++i)
      gl_lds16(vsrc0 + (size_t)i * 32768 + tt * 64, vdst + i * 2048);
  };

  stageV(0);
  stageK(0, 0);
  stageK(1, 8192);

  f16x8 qf[4][2];
#pragma unroll
  for (int mi = 0; mi < 4; ++mi)
#pragma unroll
    for (int kk = 0; kk < 2; ++kk) {
      f16x8 v;
#pragma unroll
      for (int e = 0; e < 8; ++e)
        v[e] = Qp[(size_t)(kk * 32 + hi * 8 + e) * 2048 + q0 + mi * 16 + l15];
      qf[mi][kk] = v;
    }

  const char* kb[2];
#pragma unroll
  for (int kk = 0; kk < 2; ++kk)
    kb[kk] = hbm + l15 * 128 + (((kk * 4 + hi) ^ (l15 & 7)) << 4);
  const char* vbp[2][2];
#pragma unroll
  for (int p = 0; p < 2; ++p)
#pragma unroll
    for (int c = 0; c < 2; ++c)
      vbp[p][c] = hbm + 16384 + l15 * 128 +
                  ((((4 * p + 2 * c + (hi >> 1)) ^ (l15 & 7)) << 4) + (hi & 1) * 8);

  f32x4 o[4][4] = {};
  f32x4 lacc[4] = {};
  const f32x4 Z4 = {0.f, 0.f, 0.f, 0.f};
  const f16x8 ONES8 = {(f16)1.f, (f16)1.f, (f16)1.f, (f16)1.f,
                       (f16)1.f, (f16)1.f, (f16)1.f, (f16)1.f};

#pragma unroll 1
  for (int t = 0; t < 16; ++t) {
    if (t < 15) asm volatile("s_waitcnt vmcnt(4)" ::: "memory");
    else        asm volatile("s_waitcnt vmcnt(0)" ::: "memory");
    __builtin_amdgcn_s_barrier();
    const int cbo = (t & 1) * 8192;
    f16x8 kf[4][2];
#pragma unroll
    for (int nj = 0; nj < 4; ++nj)
#pragma unroll
      for (int kk = 0; kk < 2; ++kk)
        kf[nj][kk] = *reinterpret_cast<const f16x8*>(kb[kk] + cbo + nj * 2048);
    f16x8 vf[2][4];
#pragma unroll
    for (int p = 0; p < 2; ++p)
#pragma unroll
      for (int j = 0; j < 4; ++j) {
        const f16x4 a = *reinterpret_cast<const f16x4*>(vbp[p][0] + j * 2048);
        const f16x4 c = *reinterpret_cast<const f16x4*>(vbp[p][1] + j * 2048);
        vf[p][j] = __builtin_shufflevector(a, c, 0, 1, 2, 3, 4, 5, 6, 7);
      }
    // ---- S^T = K Q^T in the drain window ----
    f32x4 s[4][4];
    __builtin_amdgcn_s_setprio(1);
#pragma unroll
    for (int nj = 0; nj < 4; ++nj)
#pragma unroll
      for (int mi = 0; mi < 4; ++mi) {
        s[nj][mi] = MFMA(kf[nj][0], qf[mi][0], Z4);
        s[nj][mi] = MFMA(kf[nj][1], qf[mi][1], s[nj][mi]);
      }
    __builtin_amdgcn_s_setprio(0);
    // ---- hoisted: exp2/pack for nj = 0,1 (trans pipe fills the window) ----
    int pkx[4][4], pky[4][4];
#pragma unroll
    for (int nj = 0; nj < 2; ++nj)
#pragma unroll
      for (int mi = 0; mi < 4; ++mi) {
        f32x4 pv;
#pragma unroll
        for (int r = 0; r < 4; ++r) pv[r] = __builtin_amdgcn_exp2f(s[nj][mi][r]);
        pkx[nj][mi] = __builtin_bit_cast(int, __builtin_amdgcn_cvt_pkrtz(pv[0], pv[1]));
        pky[nj][mi] = __builtin_bit_cast(int, __builtin_amdgcn_cvt_pkrtz(pv[2], pv[3]));
      }
    asm volatile("s_waitcnt lgkmcnt(0)" ::: "memory");
    __builtin_amdgcn_s_barrier();
    if (t < 15) stageV(t + 1);
    if (t < 14) stageK(t + 2, cbo);
    // ---- remaining exp (nj = 2,3); overlaps PV p=0 below ----
#pragma unroll
    for (int nj = 2; nj < 4; ++nj)
#pragma unroll
      for (int mi = 0; mi < 4; ++mi) {
        f32x4 pv;
#pragma unroll
        for (int r = 0; r < 4; ++r) pv[r] = __builtin_amdgcn_exp2f(s[nj][mi][r]);
        pkx[nj][mi] = __builtin_bit_cast(int, __builtin_amdgcn_cvt_pkrtz(pv[0], pv[1]));
        pky[nj][mi] = __builtin_bit_cast(int, __builtin_amdgcn_cvt_pkrtz(pv[2], pv[3]));
      }
    __builtin_amdgcn_s_setprio(1);
#pragma unroll
    for (int p = 0; p < 2; ++p)
#pragma unroll
      for (int mi = 0; mi < 4; ++mi) {
        int4 D;
        D.x = pkx[2 * p][mi];
        D.y = pky[2 * p][mi];
        D.z = pkx[2 * p + 1][mi];
        D.w = pky[2 * p + 1][mi];
        const f16x8 bk = __builtin_bit_cast(f16x8, D);
#pragma unroll
        for (int j = 0; j < 4; ++j)
          o[j][mi] = MFMA(vf[p][j], bk, o[j][mi]);
        lacc[mi] = MFMA(ONES8, bk, lacc[mi]);
      }
    __builtin_amdgcn_s_setprio(0);
  }

  __syncthreads();
  if (w >= 2) {
    char* ob = smem + (w - 2) * 16384;
    char* lb = smem + 32768 + (w - 2) * 4096;
#pragma unroll
    for (int j = 0; j < 4; ++j)
#pragma unroll
      for (int mi = 0; mi < 4; ++mi)
        *reinterpret_cast<f32x4*>(ob + (j * 4 + mi) * 1024 + lane * 16) = o[j][mi];
#pragma unroll
    for (int mi = 0; mi < 4; ++mi)
      *reinterpret_cast<f32x4*>(lb + mi * 1024 + lane * 16) = lacc[mi];
  }
  __syncthreads();
  if (w < 2) {
    const char* ob = smem + w * 16384;
    const char* lb = smem + 32768 + w * 4096;
#pragma unroll
    for (int j = 0; j < 4; ++j)
#pragma unroll
      for (int mi = 0; mi < 4; ++mi)
        o[j][mi] += *reinterpret_cast<const f32x4*>(ob + (j * 4 + mi) * 1024 + lane * 16);
#pragma unroll
    for (int mi = 0; mi < 4; ++mi)
      lacc[mi] += *reinterpret_cast<const f32x4*>(lb + mi * 1024 + lane * 16);

    float lt[4];
#pragma unroll
    for (int mi = 0; mi < 4; ++mi) lt[mi] = 1.0f / lacc[mi][0];
    asm volatile("s_waitcnt lgkmcnt(0)" ::: "memory");
    __builtin_amdgcn_sched_barrier(0);

    f16* Pw = reinterpret_cast<f16*>(smem + w * 16384);
#pragma unroll
    for (int mi = 0; mi < 4; ++mi)
#pragma unroll
      for (int j = 0; j < 4; ++j) {
        f16x4 ok;
#pragma unroll
        for (int r = 0; r < 4; ++r) ok[r] = (f16)(o[j][mi][r] * lt[mi]);
        *reinterpret_cast<f16x4*>(&Pw[(mi * 16 + l15) * 72 + j * 16 + hi * 4]) = ok;
      }
#pragma unroll
    for (int t = 0; t < 8; ++t) {
      const f16x8 v = *reinterpret_cast<const f16x8*>(&Pw[lane * 72 + t * 8]);
      *reinterpret_cast<f16x8*>(
          &Ao[((size_t)(b * 2048 + q0 + lane)) * 768 + h * 64 + t * 8]) = v;
    }
  }
}

// ---------------- proj GEMM: [8192,768] x [768,768]^T + bias -> f32 ----------------
// Double-buffered LDS, counted vmcnt(6) + raw barriers. (R18-proven version.)
__global__ __launch_bounds__(256) void gemm_proj(const f16* __restrict__ A,
                                                 const f16* __restrict__ W,
                                                 const float* __restrict__ bias,
                                                 float* __restrict__ out) {
  __shared__ f16 As[2][4096];
  __shared__ f16 Bs[2][8192];
  const int tid = threadIdx.x;
  const int lane = tid & 63;
  const int w = tid >> 6;
  const int m0 = blockIdx.x * 64;
  const int n0 = blockIdx.y * 128;
  const int wr = (w >> 1) * 32;
  const int wc = (w & 1) * 64;
  const int srow = tid >> 3;
  const int scol = (tid & 7) * 8;
  f32x4 acc[2][4] = {};

  auto stage = [&](int buf, int k0) {
#pragma unroll
    for (int i = 0; i < 2; ++i)
      gl_lds16(A + (size_t)(m0 + i * 32 + srow) * 768 + k0 + scol,
               &As[buf][(i * 32 + srow) * 64 + scol]);
#pragma unroll
    for (int i = 0; i < 4; ++i)
      gl_lds16(W + (size_t)(n0 + i * 32 + srow) * 768 + k0 + scol,
               &Bs[buf][(i * 32 + srow) * 64 + scol]);
  };
  stage(0, 0);
  stage(1, 64);

#pragma unroll 1
  for (int t = 0; t < 12; ++t) {
    if (t < 11) asm volatile("s_waitcnt vmcnt(6)" ::: "memory");
    else        asm volatile("s_waitcnt vmcnt(0)" ::: "memory");
    __builtin_amdgcn_s_barrier();
    const int cb = t & 1;
#pragma unroll
    for (int kk = 0; kk < 2; ++kk) {
      const int ko = kk * 32 + (lane >> 4) * 8;
      f16x8 af[2], bf[4];
#pragma unroll
      for (int i = 0; i < 2; ++i)
        af[i] = *reinterpret_cast<const f16x8*>(&As[cb][(wr + i * 16 + (lane & 15)) * 64 + ko]);
#pragma unroll
      for (int j = 0; j < 4; ++j)
        bf[j] = *reinterpret_cast<const f16x8*>(&Bs[cb][(wc + j * 16 + (lane & 15)) * 64 + ko]);
#pragma unroll
      for (int i = 0; i < 2; ++i)
#pragma unroll
        for (int j = 0; j < 4; ++j)
          acc[i][j] = MFMA(af[i], bf[j], acc[i][j]);
    }
    __builtin_amdgcn_s_barrier();
    if (t < 10) stage(cb, (t + 2) * 64);
  }

#pragma unroll
  for (int j = 0; j < 4; ++j) {
    const int col = n0 + wc + j * 16 + (lane & 15);
    const float bj = bias[col];
#pragma unroll
    for (int i = 0; i < 2; ++i)
#pragma unroll
      for (int r = 0; r < 4; ++r)
        out[(size_t)(m0 + wr + i * 16 + (lane >> 4) * 4 + r) * 768 + col] =
            acc[i][j][r] + bj;
  }
}

extern "C" void kernel_launch(void* const* d_in, const int* in_sizes, int n_in,
                              void* d_out, int out_size, void* d_ws, size_t ws_size,
                              hipStream_t stream) {
  const float* x      = (const float*)d_in[0];  // [4,2048,768]
  const float* w_qkv  = (const float*)d_in[1];  // [2304,768]
  const float* w_proj = (const float*)d_in[2];  // [768,768]
  const float* b_proj = (const float*)d_in[3];  // [768]
  float* out = (float*)d_out;
  char* ws = (char*)d_ws;

  f16* xh  = (f16*)(ws);              // 8192*768*2      = 12,582,912
  f16* wqh = (f16*)(ws + 12582912);   // 2304*768*2      =  3,538,944
  f16* wph = (f16*)(ws + 16121856);   // 768*768*2       =  1,179,648
  f16* Qtb = (f16*)(ws + 17301504);   // [4,12,64,2048]  = 12,582,912
  f16* Kb  = (f16*)(ws + 29884416);   // [4,12,2048,64]
  f16* Vtb = (f16*)(ws + 42467328);   // [4,12,64,2048]
  f16* Ah  = (f16*)(ws + 55050240);   // [4,2048,768]    -> total 67,633,152 B

  cvt_all<<<8448, 256, 0, stream>>>(x, w_qkv, w_proj, xh, wqh, wph);
  gemm_qkv<<<dim3(64, 18), 256, 0, stream>>>(xh, wqh, Qtb, Kb, Vtb);
  attn_fwd<<<768, 256, 0, stream>>>(Qtb, Kb, Vtb, Ah);
  gemm_proj<<<dim3(128, 6), 256, 0, stream>>>(Ah, wph, b_proj, out);
}

// Round 23
// 132.532 us; speedup vs baseline: 1.0123x; 1.0120x over previous
//
#include <hip/hip_runtime.h>
#include <hip/hip_bf16.h>
#include <cstdint>

typedef _Float16 f16;
typedef __attribute__((ext_vector_type(8))) _Float16 f16x8;
typedef __attribute__((ext_vector_type(4))) _Float16 f16x4;
typedef __attribute__((ext_vector_type(2))) _Float16 f16x2;
typedef __attribute__((ext_vector_type(4))) float f32x4;

#define MFMA(a, b, c) __builtin_amdgcn_mfma_f32_16x16x32_f16((a), (b), (c), 0, 0, 0)

__device__ static inline void gl_lds16(const void* g, void* l) {
  __builtin_amdgcn_global_load_lds(
      (__attribute__((address_space(1))) const void*)g,
      (__attribute__((address_space(3))) void*)l, 16, 0, 0);
}

// ---------------- f32 -> f16 cast, all three tensors in one launch ----------------
__global__ __launch_bounds__(256) void cvt_all(const float* __restrict__ x,
                                               const float* __restrict__ wq,
                                               const float* __restrict__ wp,
                                               f16* __restrict__ xo,
                                               f16* __restrict__ wqo,
                                               f16* __restrict__ wpo) {
  int i = blockIdx.x * 256 + threadIdx.x;
  const float* src;
  f16* dst;
  if (i < 1572864) {
    src = x; dst = xo;
  } else if (i < 1572864 + 442368) {
    i -= 1572864; src = wq; dst = wqo;
  } else {
    i -= 1572864 + 442368;
    if (i >= 147456) return;
    src = wp; dst = wpo;
  }
  const float4 v = reinterpret_cast<const float4*>(src)[i];
  f16x4 o;
  o.x = (f16)v.x; o.y = (f16)v.y; o.z = (f16)v.z; o.w = (f16)v.w;
  reinterpret_cast<f16x4*>(dst)[i] = o;
}

// ---------------- QKV GEMM: [8192,768] x [2304,768]^T ----------------
// BK=32, 32KB LDS double-buffer, counted vmcnt + raw barriers.
// Bank swizzle for 64B rows: slot ^= (row ^ row>>2) & 3.
// Outputs: Qt [B,H,D,N] (pre-scaled), K [B,H,N,D], Vt [B,H,D,N].
__global__ __launch_bounds__(256) void gemm_qkv(const f16* __restrict__ X,
                                                const f16* __restrict__ W,
                                                f16* __restrict__ Qt,
                                                f16* __restrict__ Ko,
                                                f16* __restrict__ Vt) {
  __shared__ f16 As[2][4096];
  __shared__ f16 Bs[2][4096];
  const int tid = threadIdx.x;
  const int lane = tid & 63;
  const int w = tid >> 6;
  const int l15 = lane & 15, hi = lane >> 4;
  const int m0 = blockIdx.x * 128;
  const int n0 = blockIdx.y * 128;
  const int wr = (w >> 1) * 64;
  const int wc = (w & 1) * 64;
  f32x4 acc[4][4] = {};

  const int srow0 = tid >> 2;
  const int sslot = tid & 3;
  auto stage = [&](int buf, int k0) {
#pragma unroll
    for (int i = 0; i < 2; ++i) {
      const int row = i * 64 + srow0;
      const int gs = (sslot ^ ((row ^ (row >> 2)) & 3)) * 8;
      gl_lds16(X + (size_t)(m0 + row) * 768 + k0 + gs,
               &As[buf][row * 32 + sslot * 8]);
      gl_lds16(W + (size_t)(n0 + row) * 768 + k0 + gs,
               &Bs[buf][row * 32 + sslot * 8]);
    }
  };
  stage(0, 0);
  stage(1, 32);

  const int ko = (hi ^ ((l15 ^ (l15 >> 2)) & 3)) * 8;

#pragma unroll 1
  for (int t = 0; t < 24; ++t) {
    if (t < 23) asm volatile("s_waitcnt vmcnt(4)" ::: "memory");
    else        asm volatile("s_waitcnt vmcnt(0)" ::: "memory");
    __builtin_amdgcn_s_barrier();
    const int cb = t & 1;
    f16x8 af[4], bf[4];
#pragma unroll
    for (int i = 0; i < 4; ++i)
      af[i] = *reinterpret_cast<const f16x8*>(&As[cb][(wr + i * 16 + l15) * 32 + ko]);
#pragma unroll
    for (int j = 0; j < 4; ++j)
      bf[j] = *reinterpret_cast<const f16x8*>(&Bs[cb][(wc + j * 16 + l15) * 32 + ko]);
#pragma unroll
    for (int i = 0; i < 4; ++i)
#pragma unroll
      for (int j = 0; j < 4; ++j)
        acc[i][j] = MFMA(af[i], bf[j], acc[i][j]);
    __builtin_amdgcn_s_barrier();
    if (t < 22) stage(cb, (t + 2) * 32);
  }
  // after final barrier all waves are done with As/Bs -> reuse for transpose

  const int b = m0 >> 11;
  const int nbase = (m0 & 2047) + wr;
  const int which = n0 / 768;
  const int h = ((n0 % 768) >> 6) + (wc >> 6);
  const size_t hb = (size_t)(b * 12 + h);
  const float QSCL = 0.125f * 1.44269504088896340736f;  // SCALE * log2(e)
  f16* T = &As[0][0] + w * 1280;  // 4 waves x 1280 f16 <= 8192 f16 in As

  if (which != 1) {
    f16* dst = (which == 2) ? Vt : Qt;
    const float scl = (which == 0) ? QSCL : 1.0f;
#pragma unroll
    for (int j = 0; j < 4; ++j) {
#pragma unroll
      for (int i = 0; i < 4; ++i) {
        f16x4 vv;
#pragma unroll
        for (int r = 0; r < 4; ++r) vv[r] = (f16)(acc[i][j][r] * scl);
        *reinterpret_cast<f16x4*>(&T[l15 * 72 + i * 16 + hi * 4]) = vv;
      }
      asm volatile("s_waitcnt lgkmcnt(0)" ::: "memory");
#pragma unroll
      for (int t = 0; t < 2; ++t) {
        const f16x8 v = *reinterpret_cast<const f16x8*>(
            &T[(t * 8 + (lane >> 3)) * 72 + (lane & 7) * 8]);
        const int d = j * 16 + t * 8 + (lane >> 3);
        *reinterpret_cast<f16x8*>(
            &dst[(hb * 64 + d) * 2048 + nbase + (lane & 7) * 8]) = v;
      }
      asm volatile("s_waitcnt lgkmcnt(0)" ::: "memory");
    }
  } else {
#pragma unroll
    for (int i = 0; i < 4; ++i) {
#pragma unroll
      for (int j = 0; j < 4; ++j)
#pragma unroll
        for (int r = 0; r < 4; ++r)
          T[(hi * 4 + r) * 72 + j * 16 + l15] = (f16)acc[i][j][r];
      asm volatile("s_waitcnt lgkmcnt(0)" ::: "memory");
#pragma unroll
      for (int t = 0; t < 2; ++t) {
        const f16x8 v = *reinterpret_cast<const f16x8*>(
            &T[(t * 8 + (lane >> 3)) * 72 + (lane & 7) * 8]);
        const int n = nbase + i * 16 + t * 8 + (lane >> 3);
        *reinterpret_cast<f16x8*>(
            &Ko[(hb * 2048 + n) * 64 + (lane & 7) * 8]) = v;
      }
      asm volatile("s_waitcnt lgkmcnt(0)" ::: "memory");
    }
  }
}

// ---------------- flash attention, in-block KV-split + K32 PV (sigma) ----------------
// 4 waves/block: waves 0,1 kv[0,1024), waves 2,3 kv[1024,2048), same 128 q.
// This round: K AND V double-buffered (per half: K0|K1|V0|V1, 8KB each) ->
// ONE barrier per step, no mid-step lgkm drain. Step t reads buf[t&1] while
// staging t+1 into buf[(t+1)&1]; reads are MFMA-consumed within the step, so
// they complete before the next top-of-step barrier (no overwrite race).
__global__ __launch_bounds__(256, 2) void attn_fwd(const f16* __restrict__ Qt,
                                                   const f16* __restrict__ K,
                                                   const f16* __restrict__ Vt,
                                                   f16* __restrict__ Ao) {
  __shared__ char smem[65536];  // half h @ h*32768: K0|K1@0,8192 V0|V1@16384,24576
  const int tid = threadIdx.x, lane = tid & 63, w = tid >> 6;
  const int l15 = lane & 15, hi = lane >> 4;
  const int half = tid >> 7;
  const int ptd = tid & 127;

  const int id = blockIdx.x;
  const int sw = (id & 7) * 96 + (id >> 3);
  const int bh = sw >> 4;
  const int qt = sw & 15;
  const int b = bh / 12, h = bh % 12;
  const int q0 = qt * 128 + (w & 1) * 64;
  const f16* Qp = Qt + (size_t)bh * 64 * 2048;
  const f16* Kp = K + (size_t)bh * 2048 * 64;
  const f16* Vp = Vt + (size_t)bh * 64 * 2048;

  char* hbm = smem + half * 32768;
  const int kvb = half * 1024;

  const int tr = ptd >> 3;
  const int ss = ptd & 7;
  const int ssw = ss ^ (tr & 7);
  const f16* ksrc0 = Kp + (size_t)(kvb + tr) * 64 + ssw * 8;
  const f16* vsrc0 = Vp + (size_t)tr * 2048 + kvb + ssw * 8;
  char* kdst = hbm + tr * 128 + ss * 16;
  char* vdst = hbm + 16384 + tr * 128 + ss * 16;

  auto stageK = [&](int tt, int bufo) {
#pragma unroll
    for (int i = 0; i < 4; ++i)
      gl_lds16(ksrc0 + (size_t)(tt * 64 + i * 16) * 64, kdst + bufo + i * 2048);
  };
  auto stageV = [&](int tt, int bufo) {
#pragma unroll
    for (int i = 0; i < 4; ++i)
      gl_lds16(vsrc0 + (size_t)i * 32768 + tt * 64, vdst + bufo + i * 2048);
  };

  // prologue: tile 0 into buffers 0
  stageV(0, 0);
  stageK(0, 0);

  f16x8 qf[4][2];
#pragma unroll
  for (int mi = 0; mi < 4; ++mi)
#pragma unroll
    for (int kk = 0; kk < 2; ++kk) {
      f16x8 v;
#pragma unroll
      for (int e = 0; e < 8; ++e)
        v[e] = Qp[(size_t)(kk * 32 + hi * 8 + e) * 2048 + q0 + mi * 16 + l15];
      qf[mi][kk] = v;
    }

  const char* kb[2];
#pragma unroll
  for (int kk = 0; kk < 2; ++kk)
    kb[kk] = hbm + l15 * 128 + (((kk * 4 + hi) ^ (l15 & 7)) << 4);
  const char* vbp[2][2];
#pragma unroll
  for (int p = 0; p < 2; ++p)
#pragma unroll
    for (int c = 0; c < 2; ++c)
      vbp[p][c] = hbm + 16384 + l15 * 128 +
                  ((((4 * p + 2 * c + (hi >> 1)) ^ (l15 & 7)) << 4) + (hi & 1) * 8);

  f32x4 o[4][4] = {};
  f32x4 lacc[4] = {};
  const f32x4 Z4 = {0.f, 0.f, 0.f, 0.f};
  const f16x8 ONES8 = {(f16)1.f, (f16)1.f, (f16)1.f, (f16)1.f,
                       (f16)1.f, (f16)1.f, (f16)1.f, (f16)1.f};

#pragma unroll 1
  for (int t = 0; t < 16; ++t) {
    // tile t's loads were issued a full compute phase ago -> near-free drain
    asm volatile("s_waitcnt vmcnt(0)" ::: "memory");
    __builtin_amdgcn_s_barrier();
    const int cbo = (t & 1) * 8192;
    f16x8 kf[4][2];
#pragma unroll
    for (int nj = 0; nj < 4; ++nj)
#pragma unroll
      for (int kk = 0; kk < 2; ++kk)
        kf[nj][kk] = *reinterpret_cast<const f16x8*>(kb[kk] + cbo + nj * 2048);
    f16x8 vf[2][4];
#pragma unroll
    for (int p = 0; p < 2; ++p)
#pragma unroll
      for (int j = 0; j < 4; ++j) {
        const f16x4 a = *reinterpret_cast<const f16x4*>(vbp[p][0] + cbo + j * 2048);
        const f16x4 c = *reinterpret_cast<const f16x4*>(vbp[p][1] + cbo + j * 2048);
        vf[p][j] = __builtin_shufflevector(a, c, 0, 1, 2, 3, 4, 5, 6, 7);
      }
    // stage tile t+1 into the OTHER buffers (no conflict with this step's reads)
    if (t < 15) {
      const int nbo = ((t + 1) & 1) * 8192;
      stageV(t + 1, nbo);
      stageK(t + 1, nbo);
    }
    // ---- S^T = K Q^T (compiler inserts partial lgkm waits before MFMAs) ----
    f32x4 s[4][4];
    __builtin_amdgcn_s_setprio(1);
#pragma unroll
    for (int nj = 0; nj < 4; ++nj)
#pragma unroll
      for (int mi = 0; mi < 4; ++mi) {
        s[nj][mi] = MFMA(kf[nj][0], qf[mi][0], Z4);
        s[nj][mi] = MFMA(kf[nj][1], qf[mi][1], s[nj][mi]);
      }
    __builtin_amdgcn_s_setprio(0);
    // ---- p = exp2(s); pack to dwords (these ARE the sigma B-frag dwords) ----
    int pkx[4][4], pky[4][4];
#pragma unroll
    for (int nj = 0; nj < 4; ++nj)
#pragma unroll
      for (int mi = 0; mi < 4; ++mi) {
        f32x4 pv;
#pragma unroll
        for (int r = 0; r < 4; ++r) pv[r] = __builtin_amdgcn_exp2f(s[nj][mi][r]);
        pkx[nj][mi] = __builtin_bit_cast(int, __builtin_amdgcn_cvt_pkrtz(pv[0], pv[1]));
        pky[nj][mi] = __builtin_bit_cast(int, __builtin_amdgcn_cvt_pkrtz(pv[2], pv[3]));
      }
    // ---- O^T += V^T P (K=32, sigma); l += ones^T P via MFMA ----
    __builtin_amdgcn_s_setprio(1);
#pragma unroll
    for (int p = 0; p < 2; ++p)
#pragma unroll
      for (int mi = 0; mi < 4; ++mi) {
        int4 D;
        D.x = pkx[2 * p][mi];
        D.y = pky[2 * p][mi];
        D.z = pkx[2 * p + 1][mi];
        D.w = pky[2 * p + 1][mi];
        const f16x8 bk = __builtin_bit_cast(f16x8, D);
#pragma unroll
        for (int j = 0; j < 4; ++j)
          o[j][mi] = MFMA(vf[p][j], bk, o[j][mi]);
        lacc[mi] = MFMA(ONES8, bk, lacc[mi]);
      }
    __builtin_amdgcn_s_setprio(0);
  }

  // ---- combine halves (plain sum; no-bias softmax) ----
  __syncthreads();
  if (w >= 2) {
    char* ob = smem + (w - 2) * 16384;
    char* lb = smem + 32768 + (w - 2) * 4096;
#pragma unroll
    for (int j = 0; j < 4; ++j)
#pragma unroll
      for (int mi = 0; mi < 4; ++mi)
        *reinterpret_cast<f32x4*>(ob + (j * 4 + mi) * 1024 + lane * 16) = o[j][mi];
#pragma unroll
    for (int mi = 0; mi < 4; ++mi)
      *reinterpret_cast<f32x4*>(lb + mi * 1024 + lane * 16) = lacc[mi];
  }
  __syncthreads();
  if (w < 2) {
    const char* ob = smem + w * 16384;
    const char* lb = smem + 32768 + w * 4096;
#pragma unroll
    for (int j = 0; j < 4; ++j)
#pragma unroll
      for (int mi = 0; mi < 4; ++mi)
        o[j][mi] += *reinterpret_cast<const f32x4*>(ob + (j * 4 + mi) * 1024 + lane * 16);
#pragma unroll
    for (int mi = 0; mi < 4; ++mi)
      lacc[mi] += *reinterpret_cast<const f32x4*>(lb + mi * 1024 + lane * 16);

    float lt[4];
#pragma unroll
    for (int mi = 0; mi < 4; ++mi) lt[mi] = 1.0f / lacc[mi][0];
    asm volatile("s_waitcnt lgkmcnt(0)" ::: "memory");
    __builtin_amdgcn_sched_barrier(0);

    f16* Pw = reinterpret_cast<f16*>(smem + w * 16384);
#pragma unroll
    for (int mi = 0; mi < 4; ++mi)
#pragma unroll
      for (int j = 0; j < 4; ++j) {
        f16x4 ok;
#pragma unroll
        for (int r = 0; r < 4; ++r) ok[r] = (f16)(o[j][mi][r] * lt[mi]);
        *reinterpret_cast<f16x4*>(&Pw[(mi * 16 + l15) * 72 + j * 16 + hi * 4]) = ok;
      }
#pragma unroll
    for (int t = 0; t < 8; ++t) {
      const f16x8 v = *reinterpret_cast<const f16x8*>(&Pw[lane * 72 + t * 8]);
      *reinterpret_cast<f16x8*>(
          &Ao[((size_t)(b * 2048 + q0 + lane)) * 768 + h * 64 + t * 8]) = v;
    }
  }
}

// ---------------- proj GEMM: [8192,768] x [768,768]^T + bias -> f32 ----------------
// Double-buffered LDS, counted vmcnt(6) + raw barriers. (R18-proven version.)
__global__ __launch_bounds__(256) void gemm_proj(const f16* __restrict__ A,
                                                 const f16* __restrict__ W,
                                                 const float* __restrict__ bias,
                                                 float* __restrict__ out) {
  __shared__ f16 As[2][4096];
  __shared__ f16 Bs[2][8192];
  const int tid = threadIdx.x;
  const int lane = tid & 63;
  const int w = tid >> 6;
  const int m0 = blockIdx.x * 64;
  const int n0 = blockIdx.y * 128;
  const int wr = (w >> 1) * 32;
  const int wc = (w & 1) * 64;
  const int srow = tid >> 3;
  const int scol = (tid & 7) * 8;
  f32x4 acc[2][4] = {};

  auto stage = [&](int buf, int k0) {
#pragma unroll
    for (int i = 0; i < 2; ++i)
      gl_lds16(A + (size_t)(m0 + i * 32 + srow) * 768 + k0 + scol,
               &As[buf][(i * 32 + srow) * 64 + scol]);
#pragma unroll
    for (int i = 0; i < 4; ++i)
      gl_lds16(W + (size_t)(n0 + i * 32 + srow) * 768 + k0 + scol,
               &Bs[buf][(i * 32 + srow) * 64 + scol]);
  };
  stage(0, 0);
  stage(1, 64);

#pragma unroll 1
  for (int t = 0; t < 12; ++t) {
    if (t < 11) asm volatile("s_waitcnt vmcnt(6)" ::: "memory");
    else        asm volatile("s_waitcnt vmcnt(0)" ::: "memory");
    __builtin_amdgcn_s_barrier();
    const int cb = t & 1;
#pragma unroll
    for (int kk = 0; kk < 2; ++kk) {
      const int ko = kk * 32 + (lane >> 4) * 8;
      f16x8 af[2], bf[4];
#pragma unroll
      for (int i = 0; i < 2; ++i)
        af[i] = *reinterpret_cast<const f16x8*>(&As[cb][(wr + i * 16 + (lane & 15)) * 64 + ko]);
#pragma unroll
      for (int j = 0; j < 4; ++j)
        bf[j] = *reinterpret_cast<const f16x8*>(&Bs[cb][(wc + j * 16 + (lane & 15)) * 64 + ko]);
#pragma unroll
      for (int i = 0; i < 2; ++i)
#pragma unroll
        for (int j = 0; j < 4; ++j)
          acc[i][j] = MFMA(af[i], bf[j], acc[i][j]);
    }
    __builtin_amdgcn_s_barrier();
    if (t < 10) stage(cb, (t + 2) * 64);
  }

#pragma unroll
  for (int j = 0; j < 4; ++j) {
    const int col = n0 + wc + j * 16 + (lane & 15);
    const float bj = bias[col];
#pragma unroll
    for (int i = 0; i < 2; ++i)
#pragma unroll
      for (int r = 0; r < 4; ++r)
        out[(size_t)(m0 + wr + i * 16 + (lane >> 4) * 4 + r) * 768 + col] =
            acc[i][j][r] + bj;
  }
}

extern "C" void kernel_launch(void* const* d_in, const int* in_sizes, int n_in,
                              void* d_out, int out_size, void* d_ws, size_t ws_size,
                              hipStream_t stream) {
  const float* x      = (const float*)d_in[0];  // [4,2048,768]
  const float* w_qkv  = (const float*)d_in[1];  // [2304,768]
  const float* w_proj = (const float*)d_in[2];  // [768,768]
  const float* b_proj = (const float*)d_in[3];  // [768]
  float* out = (float*)d_out;
  char* ws = (char*)d_ws;

  f16* xh  = (f16*)(ws);              // 8192*768*2      = 12,582,912
  f16* wqh = (f16*)(ws + 12582912);   // 2304*768*2      =  3,538,944
  f16* wph = (f16*)(ws + 16121856);   // 768*768*2       =  1,179,648
  f16* Qtb = (f16*)(ws + 17301504);   // [4,12,64,2048]  = 12,582,912
  f16* Kb  = (f16*)(ws + 29884416);   // [4,12,2048,64]
  f16* Vtb = (f16*)(ws + 42467328);   // [4,12,64,2048]
  f16* Ah  = (f16*)(ws + 55050240);   // [4,2048,768]    -> total 67,633,152 B

  cvt_all<<<8448, 256, 0, stream>>>(x, w_qkv, w_proj, xh, wqh, wph);
  gemm_qkv<<<dim3(64, 18), 256, 0, stream>>>(xh, wqh, Qtb, Kb, Vtb);
  attn_fwd<<<768, 256, 0, stream>>>(Qtb, Kb, Vtb, Ah);
  gemm_proj<<<dim3(128, 6), 256, 0, stream>>>(Ah, wph, b_proj, out);
}